// Round 9
// baseline (131.494 us; speedup 1.0000x reference)
//
#include <hip/hip_runtime.h>

namespace {
constexpr int NB = 128;
constexpr int NR = 512;
constexpr int ND = 256;
constexpr int NA = 14;

using short8 = __attribute__((ext_vector_type(8))) short;
using f32x4  = __attribute__((ext_vector_type(4))) float;

// workspace layout (ushort elements for weights, then rmap ints)
constexpr size_t WH_US  = (size_t)40 * 16 * 8 * 64 * 8;   // 2,621,440
constexpr size_t W0_OFF = WH_US;
constexpr size_t W0_US  = (size_t)20 * 16 * 64 * 8;       // 163,840
constexpr size_t RMAP_BYTE_OFF = (WH_US + W0_US) * 2;     // 5,570,560
constexpr size_t WS_NEEDED = RMAP_BYTE_OFF + NR * sizeof(int);

__device__ __forceinline__ unsigned short f2bf(float f) {
    unsigned int u = __float_as_uint(f);
    u = (u + 0x7FFFu + ((u >> 16) & 1u)) >> 16;           // RNE
    return (unsigned short)u;
}
}

// ---- merged prep: conv_wh (1280 blk) | conv_w0 (80 blk) | rmap (1 blk) ------
__global__ __launch_bounds__(256) void prep_all(
    const float* __restrict__ Wh, const float* __restrict__ W0,
    const int* __restrict__ type_ids,
    unsigned short* __restrict__ ws, int* __restrict__ rmap)
{
    __shared__ int tl[NR];
    const int bid = blockIdx.x, tid = threadIdx.x;
    if (bid < 1280) {
        // Wh fp32 -> bf16, A-fragment order
        const int g = bid * 256 + tid;                   // < 327680
        const int lane = g & 63, kt = (g >> 6) & 7, mt = (g >> 9) & 15, tw = g >> 13;
        const int v = mt * 16 + (lane & 15);
        const int u0 = kt * 32 + (lane >> 4) * 8;
        const float* src = Wh + ((size_t)tw * ND + v) * ND + u0;
        unsigned short o[8];
#pragma unroll
        for (int j = 0; j < 8; ++j) o[j] = f2bf(src[j]);
        uint4 pk;
        pk.x = o[0] | ((unsigned)o[1] << 16); pk.y = o[2] | ((unsigned)o[3] << 16);
        pk.z = o[4] | ((unsigned)o[5] << 16); pk.w = o[6] | ((unsigned)o[7] << 16);
        *reinterpret_cast<uint4*>(ws + (size_t)g * 8) = pk;
    } else if (bid < 1360) {
        // W0 fp32 -> bf16, zero-padded K 14->32
        const int g = (bid - 1280) * 256 + tid;          // < 20480
        const int lane = g & 63, mt = (g >> 6) & 15, t = g >> 10;
        const int v = mt * 16 + (lane & 15);
        const int a0 = (lane >> 4) * 8;
        unsigned short o[8];
#pragma unroll
        for (int j = 0; j < 8; ++j) {
            const int a = a0 + j;
            o[j] = (a < NA) ? f2bf(W0[((size_t)t * ND + v) * NA + a]) : (unsigned short)0;
        }
        uint4 pk;
        pk.x = o[0] | ((unsigned)o[1] << 16); pk.y = o[2] | ((unsigned)o[3] << 16);
        pk.z = o[4] | ((unsigned)o[5] << 16); pk.w = o[6] | ((unsigned)o[7] << 16);
        *reinterpret_cast<uint4*>(ws + W0_OFF + (size_t)g * 8) = pk;
    } else {
        // type-sorted residue map (stable counting order, deterministic)
        tl[tid] = type_ids[tid];
        tl[tid + 256] = type_ids[tid + 256];
        __syncthreads();
        for (int i = tid; i < NR; i += 256) {
            const int myt = tl[i];
            int pos = 0;
            for (int j = 0; j < NR; ++j) {
                const int tj = tl[j];
                pos += (tj < myt) || (tj == myt && j < i);
            }
            rmap[pos] = i;
        }
    }
}

// ---- main fused kernel ------------------------------------------------------
// 2048 blocks, 512 threads (8 waves). XCD-affine: xcd = bid&7 owns sorted
// residue positions [64*xcd, 64*xcd+64) -> ~2-3 types -> Wh L2-resident.
// Tile = 96 cols (32 batches). Wave w owns v in [32w, 32w+32): acc[2][6].
// LDS 50688B x 3 = 152KB <= 160KB; launch_bounds(512,6) -> 3 blocks/CU,
// 24 waves/CU, 85-VGPR budget (live set ~80: 48 acc + 8 a + 4 bf + misc).
__global__ __launch_bounds__(512, 6) void residues_mfma(
    const float* __restrict__ x, const unsigned short* __restrict__ wsw,
    const int* __restrict__ rmap, const int* __restrict__ type_ids,
    const int* __restrict__ res_idx, float* __restrict__ out, int n_atoms)
{
    const int tid = threadIdx.x, lane = tid & 63, w = tid >> 6;
    const int xcd = blockIdx.x & 7, j = blockIdx.x >> 3;      // j in [0,256)
    const int r = rmap[xcd * 64 + (j >> 2)];
    const int b0 = (j & 3) * 32;
    const int ri = res_idx[r], t = type_ids[r];

    // HT[96][264] bf16 (50688B). Aliased (disjoint lifetimes):
    //   dltT[96][40] bf16 @ base ; fst[96][132] f32 @ base (exactly 50688B)
    __shared__ __align__(16) unsigned short HT[96 * 264];
    unsigned short* dltT = HT;

    // hoist layer-0 A fragments (depend only on t)
    const unsigned short* w0b = wsw + W0_OFF + (size_t)t * (16 * 64 * 8);
    short8 a0[2];
#pragma unroll
    for (int mi = 0; mi < 2; ++mi)
        a0[mi] = *reinterpret_cast<const short8*>(w0b + (((w * 2 + mi) * 64) + lane) * 8);

    // ---- fused stage: dltT (bf16, K padded to 32) + pos_ca -----------------
#pragma unroll
    for (int it = 0; it < 2; ++it) {
        const int task = tid + it * 512;           // 0..1023 = 32 bl x 32 k
        const int bl = task >> 5, k = task & 31;
        const float* xb = x + (size_t)(b0 + bl) * n_atoms * 3;
        if (k < 16) {
            int atom = ri + k; if (atom > n_atoms - 1) atom = n_atoms - 1;
            const float* src  = xb + (size_t)atom * 3;
            const float* root = xb + (size_t)(ri + 1) * 3;
#pragma unroll
            for (int c = 0; c < 3; ++c)
                dltT[(bl * 3 + c) * 40 + k] = f2bf(src[c] - root[c]);
            if (k == 1) {
#pragma unroll
                for (int c = 0; c < 3; ++c)
                    out[((size_t)(b0 + bl) * NR + r) * 3 + c] = root[c];
            }
        } else {
#pragma unroll
            for (int c = 0; c < 3; ++c)
                dltT[(bl * 3 + c) * 40 + k] = 0;
        }
    }
    __syncthreads();

    f32x4 acc[2][6];
#pragma unroll
    for (int mi = 0; mi < 2; ++mi)
#pragma unroll
        for (int ni = 0; ni < 6; ++ni) acc[mi][ni] = f32x4{0.f, 0.f, 0.f, 0.f};

    // ---- layer 0: K=32 (padded), A hoisted, B from dltT --------------------
#pragma unroll
    for (int ni = 0; ni < 6; ++ni) {
        const short8 bf = *reinterpret_cast<const short8*>(&dltT[(ni * 16 + (lane & 15)) * 40 + (lane >> 4) * 8]);
#pragma unroll
        for (int mi = 0; mi < 2; ++mi)
            acc[mi][ni] = __builtin_amdgcn_mfma_f32_16x16x32_bf16(a0[mi], bf, acc[mi][ni], 0, 0, 0);
    }
    __syncthreads();   // dltT reads done before HT overwrite (aliased)

    // ---- hidden layers ------------------------------------------------------
#pragma unroll 1
    for (int l = 0; l < 2; ++l) {
#pragma unroll
        for (int mi = 0; mi < 2; ++mi)
#pragma unroll
            for (int ni = 0; ni < 6; ++ni) {
                const int v0 = w * 32 + mi * 16 + (lane >> 4) * 4;
                const int n  = ni * 16 + (lane & 15);
                const unsigned lo = (unsigned)f2bf(acc[mi][ni][0]) | ((unsigned)f2bf(acc[mi][ni][1]) << 16);
                const unsigned hi = (unsigned)f2bf(acc[mi][ni][2]) | ((unsigned)f2bf(acc[mi][ni][3]) << 16);
                *reinterpret_cast<uint2*>(&HT[n * 264 + v0]) = make_uint2(lo, hi);
            }
        __syncthreads();

#pragma unroll
        for (int mi = 0; mi < 2; ++mi)
#pragma unroll
            for (int ni = 0; ni < 6; ++ni) acc[mi][ni] = f32x4{0.f, 0.f, 0.f, 0.f};

        const unsigned short* wl = wsw + (size_t)(t * 2 + l) * (16 * 8 * 64 * 8);
#pragma unroll 1
        for (int kt = 0; kt < 8; ++kt) {
            short8 a[2];
#pragma unroll
            for (int mi = 0; mi < 2; ++mi)
                a[mi] = *reinterpret_cast<const short8*>(wl + ((((w * 2 + mi) * 8 + kt) * 64) + lane) * 8);
#pragma unroll
            for (int ni = 0; ni < 6; ++ni) {
                const short8 bf = *reinterpret_cast<const short8*>(&HT[(ni * 16 + (lane & 15)) * 264 + kt * 32 + (lane >> 4) * 8]);
#pragma unroll
                for (int mi = 0; mi < 2; ++mi)
                    acc[mi][ni] = __builtin_amdgcn_mfma_f32_16x16x32_bf16(a[mi], bf, acc[mi][ni], 0, 0, 0);
            }
        }
        if (l == 0) __syncthreads();
    }

    // ---- epilogue: fp32 restage through LDS (2 v-halves), nt f32x4 stores --
    float* fst  = reinterpret_cast<float*>(HT);         // [96][132]
    float* outh = out + (size_t)NB * NR * 3;
#pragma unroll 1
    for (int p = 0; p < 2; ++p) {
        __syncthreads();                                // p=0: HT reads done; p=1: stores done
        if ((w >> 2) == p) {                            // waves owning v in [128p,128p+128)
            const int wq = w & 3;
#pragma unroll
            for (int mi = 0; mi < 2; ++mi)
#pragma unroll
                for (int ni = 0; ni < 6; ++ni) {
                    const int n = ni * 16 + (lane & 15);
#pragma unroll
                    for (int jj = 0; jj < 4; ++jj) {
                        const int vl = wq * 32 + mi * 16 + (lane >> 4) * 4 + jj;
                        fst[n * 132 + vl] = acc[mi][ni][jj];
                    }
                }
        }
        __syncthreads();
#pragma unroll
        for (int i = 0; i < 6; ++i) {
            const int idx = tid + i * 512;        // 0..3071
            const int bl = idx / 96, g = idx % 96;
            f32x4 v4;
#pragma unroll
            for (int e = 0; e < 4; ++e) {
                const int f = 4 * g + e, c = f % 3, vp = f / 3;   // vp in [0,128)
                v4[e] = fst[(bl * 3 + c) * 132 + vp];
            }
            __builtin_nontemporal_store(v4,
                reinterpret_cast<f32x4*>(&outh[(((size_t)(b0 + bl) * NR + r) * (ND * 3)) + p * 384 + 4 * g]));
        }
    }
}

// ---- fallback (round-2 verified VALU kernel) if ws too small ---------------
__global__ __launch_bounds__(256, 3) void residues_fused_fb(
    const float* __restrict__ x, const float* __restrict__ W0,
    const float* __restrict__ Wh, const int* __restrict__ type_ids,
    const int* __restrict__ res_idx, float* __restrict__ out, int n_atoms)
{
    const int tid = threadIdx.x;
    const int r = blockIdx.x >> 4;
    const int b0 = (blockIdx.x & 15) * 8;
    const int ri = res_idx[r], t = type_ids[r];
    __shared__ float dlt[NA][24];
    __shared__ float hA[ND][24];
    __shared__ float hB[ND][24];
    for (int idx = tid; idx < 8 * NA * 3; idx += 256) {
        const int bb = idx / (NA * 3), rem = idx % (NA * 3);
        const int a = rem / 3, c = rem % 3, b = b0 + bb;
        int ca = ri + a; if (ca > n_atoms - 1) ca = n_atoms - 1;
        const float root = x[((size_t)b * n_atoms + (ri + 1)) * 3 + c];
        dlt[a][bb * 3 + c] = x[((size_t)b * n_atoms + ca) * 3 + c] - root;
        if (a == 0) out[((size_t)b * NR + r) * 3 + c] = root;
    }
    __syncthreads();
    {
        const float* w0row = W0 + ((size_t)t * ND + tid) * NA;
        float acc[24];
#pragma unroll
        for (int n = 0; n < 24; ++n) acc[n] = 0.f;
#pragma unroll
        for (int a = 0; a < NA; ++a) {
            const float wv = w0row[a];
#pragma unroll
            for (int n = 0; n < 24; ++n) acc[n] += wv * dlt[a][n];
        }
#pragma unroll
        for (int n = 0; n < 24; ++n) hA[tid][n] = acc[n];
    }
    __syncthreads();
    const float* whbase = Wh + (size_t)t * 2 * ND * ND;
#pragma unroll
    for (int l = 0; l < 2; ++l) {
        const float* wrow = whbase + ((size_t)l * ND + tid) * ND;
        const float (*hin)[24] = (l == 0) ? hA : hB;
        float (*hout)[24]      = (l == 0) ? hB : hA;
        float acc[24];
#pragma unroll
        for (int n = 0; n < 24; ++n) acc[n] = 0.f;
        for (int u = 0; u < ND; ++u) {
            const float wv = wrow[u];
#pragma unroll
            for (int n = 0; n < 24; ++n) acc[n] += wv * hin[u][n];
        }
#pragma unroll
        for (int n = 0; n < 24; ++n) hout[tid][n] = acc[n];
        __syncthreads();
    }
    float* outh = out + (size_t)NB * NR * 3;
#pragma unroll
    for (int bb = 0; bb < 8; ++bb) {
        const size_t base = ((size_t)((b0 + bb) * NR + r)) * (ND * 3);
#pragma unroll
        for (int it = 0; it < 3; ++it) {
            const int g = it * 256 + tid;
            outh[base + g] = hA[g / 3][bb * 3 + g % 3];
        }
    }
}

extern "C" void kernel_launch(void* const* d_in, const int* in_sizes, int n_in,
                              void* d_out, int out_size, void* d_ws, size_t ws_size,
                              hipStream_t stream) {
    const float* x        = (const float*)d_in[0];
    const float* W0       = (const float*)d_in[1];
    const float* Wh       = (const float*)d_in[2];
    const int*   type_ids = (const int*)d_in[3];
    const int*   res_idx  = (const int*)d_in[4];
    float* out = (float*)d_out;
    const int n_atoms = in_sizes[0] / (NB * 3);

    if (ws_size >= WS_NEEDED) {
        unsigned short* wsw = (unsigned short*)d_ws;
        int* rmap = (int*)((char*)d_ws + RMAP_BYTE_OFF);
        prep_all<<<1361, 256, 0, stream>>>(Wh, W0, type_ids, wsw, rmap);
        residues_mfma<<<NR * 4, 512, 0, stream>>>(x, wsw, rmap, type_ids, res_idx, out, n_atoms);
    } else {
        residues_fused_fb<<<NR * 16, 256, 0, stream>>>(x, W0, Wh, type_ids, res_idx, out, n_atoms);
    }
}

// Round 10
// 108.108 us; speedup vs baseline: 1.2163x; 1.2163x over previous
//
#include <hip/hip_runtime.h>

namespace {
constexpr int NB = 128;
constexpr int NR = 512;
constexpr int ND = 256;
constexpr int NA = 14;

using short8 = __attribute__((ext_vector_type(8))) short;
using f32x4  = __attribute__((ext_vector_type(4))) float;

// workspace layout (ushort elements for weights, then rmap ints)
constexpr size_t WH_US  = (size_t)40 * 16 * 8 * 64 * 8;   // 2,621,440
constexpr size_t W0_OFF = WH_US;
constexpr size_t W0_US  = (size_t)20 * 16 * 64 * 8;       // 163,840
constexpr size_t RMAP_BYTE_OFF = (WH_US + W0_US) * 2;     // 5,570,560
constexpr size_t WS_NEEDED = RMAP_BYTE_OFF + NR * sizeof(int);

__device__ __forceinline__ unsigned short f2bf(float f) {
    unsigned int u = __float_as_uint(f);
    u = (u + 0x7FFFu + ((u >> 16) & 1u)) >> 16;           // RNE
    return (unsigned short)u;
}
// bank-decorrelation swizzle for the fst v-index (applied on write AND read):
// breaks the +32/+64-word aliasing (96 words = 3 rows == 0 mod 32 banks)
__device__ __forceinline__ int vswz(int v) { return v ^ (((v >> 5) & 3) << 3); }
}

// ---- merged prep: conv_wh (1280 blk) | conv_w0 (80 blk) | rmap (1 blk) ------
__global__ __launch_bounds__(256) void prep_all(
    const float* __restrict__ Wh, const float* __restrict__ W0,
    const int* __restrict__ type_ids,
    unsigned short* __restrict__ ws, int* __restrict__ rmap)
{
    __shared__ int tl[NR];
    const int bid = blockIdx.x, tid = threadIdx.x;
    if (bid < 1280) {
        // Wh fp32 -> bf16, A-fragment order
        const int g = bid * 256 + tid;                   // < 327680
        const int lane = g & 63, kt = (g >> 6) & 7, mt = (g >> 9) & 15, tw = g >> 13;
        const int v = mt * 16 + (lane & 15);
        const int u0 = kt * 32 + (lane >> 4) * 8;
        const float* src = Wh + ((size_t)tw * ND + v) * ND + u0;
        unsigned short o[8];
#pragma unroll
        for (int j = 0; j < 8; ++j) o[j] = f2bf(src[j]);
        uint4 pk;
        pk.x = o[0] | ((unsigned)o[1] << 16); pk.y = o[2] | ((unsigned)o[3] << 16);
        pk.z = o[4] | ((unsigned)o[5] << 16); pk.w = o[6] | ((unsigned)o[7] << 16);
        *reinterpret_cast<uint4*>(ws + (size_t)g * 8) = pk;
    } else if (bid < 1360) {
        // W0 fp32 -> bf16, zero-padded K 14->32
        const int g = (bid - 1280) * 256 + tid;          // < 20480
        const int lane = g & 63, mt = (g >> 6) & 15, t = g >> 10;
        const int v = mt * 16 + (lane & 15);
        const int a0 = (lane >> 4) * 8;
        unsigned short o[8];
#pragma unroll
        for (int j = 0; j < 8; ++j) {
            const int a = a0 + j;
            o[j] = (a < NA) ? f2bf(W0[((size_t)t * ND + v) * NA + a]) : (unsigned short)0;
        }
        uint4 pk;
        pk.x = o[0] | ((unsigned)o[1] << 16); pk.y = o[2] | ((unsigned)o[3] << 16);
        pk.z = o[4] | ((unsigned)o[5] << 16); pk.w = o[6] | ((unsigned)o[7] << 16);
        *reinterpret_cast<uint4*>(ws + W0_OFF + (size_t)g * 8) = pk;
    } else {
        // type-sorted residue map (stable counting order, deterministic)
        tl[tid] = type_ids[tid];
        tl[tid + 256] = type_ids[tid + 256];
        __syncthreads();
        for (int i = tid; i < NR; i += 256) {
            const int myt = tl[i];
            int pos = 0;
            for (int j = 0; j < NR; ++j) {
                const int tj = tl[j];
                pos += (tj < myt) || (tj == myt && j < i);
            }
            rmap[pos] = i;
        }
    }
}

// ---- main fused kernel ------------------------------------------------------
// 4096 blocks, 512 threads (8 waves). XCD-affine sorted mapping (r8-proven).
// Tile = 48 cols (16 batches). Wave w owns v in [32w, 32w+32): acc[2][3] = 24.
// LDS union 49920B -> 3 blocks/CU; (512,6) budget 85 vs ~60 live -> no spill.
// Single-pass epilogue: fst[48][260] f32 holds all 256 v; XOR-swizzled banks.
__global__ __launch_bounds__(512, 6) void residues_mfma(
    const float* __restrict__ x, const unsigned short* __restrict__ wsw,
    const int* __restrict__ rmap, const int* __restrict__ type_ids,
    const int* __restrict__ res_idx, float* __restrict__ out, int n_atoms)
{
    const int tid = threadIdx.x, lane = tid & 63, w = tid >> 6;
    const int xcd = blockIdx.x & 7, j = blockIdx.x >> 3;      // j in [0,512)
    const int r = rmap[xcd * 64 + (j >> 3)];
    const int b0 = (j & 7) * 16;
    const int ri = res_idx[r], t = type_ids[r];

    // LDS union (disjoint lifetimes):
    //   dltT[48][40] bf16 (3840B) -> HT[48][264] bf16 (25344B) -> fst[48][260] f32 (49920B)
    __shared__ __align__(16) float fst[48 * 260];
    unsigned short* dltT = reinterpret_cast<unsigned short*>(fst);
    unsigned short* HT   = reinterpret_cast<unsigned short*>(fst);

    // hoist layer-0 A fragments (depend only on t)
    const unsigned short* w0b = wsw + W0_OFF + (size_t)t * (16 * 64 * 8);
    short8 a0[2];
#pragma unroll
    for (int mi = 0; mi < 2; ++mi)
        a0[mi] = *reinterpret_cast<const short8*>(w0b + (((w * 2 + mi) * 64) + lane) * 8);

    // ---- fused stage: dltT (bf16, K padded to 32) + pos_ca -----------------
    {
        const int bl = tid >> 5, k = tid & 31;     // 512 tasks = 16 bl x 32 k
        const float* xb = x + (size_t)(b0 + bl) * n_atoms * 3;
        if (k < 16) {
            int atom = ri + k; if (atom > n_atoms - 1) atom = n_atoms - 1;
            const float* src  = xb + (size_t)atom * 3;
            const float* root = xb + (size_t)(ri + 1) * 3;
#pragma unroll
            for (int c = 0; c < 3; ++c)
                dltT[(bl * 3 + c) * 40 + k] = f2bf(src[c] - root[c]);
            if (k == 1) {
#pragma unroll
                for (int c = 0; c < 3; ++c)
                    out[((size_t)(b0 + bl) * NR + r) * 3 + c] = root[c];
            }
        } else {
#pragma unroll
            for (int c = 0; c < 3; ++c)
                dltT[(bl * 3 + c) * 40 + k] = 0;
        }
    }
    __syncthreads();

    f32x4 acc[2][3];
#pragma unroll
    for (int mi = 0; mi < 2; ++mi)
#pragma unroll
        for (int ni = 0; ni < 3; ++ni) acc[mi][ni] = f32x4{0.f, 0.f, 0.f, 0.f};

    // ---- layer 0: K=32 (padded), A hoisted, B from dltT --------------------
    {
        short8 bf[3];
#pragma unroll
        for (int ni = 0; ni < 3; ++ni)
            bf[ni] = *reinterpret_cast<const short8*>(&dltT[(ni * 16 + (lane & 15)) * 40 + (lane >> 4) * 8]);
#pragma unroll
        for (int mi = 0; mi < 2; ++mi)
#pragma unroll
            for (int ni = 0; ni < 3; ++ni)
                acc[mi][ni] = __builtin_amdgcn_mfma_f32_16x16x32_bf16(a0[mi], bf[ni], acc[mi][ni], 0, 0, 0);
    }
    __syncthreads();   // dltT reads done before HT overwrite (aliased)

    // ---- hidden layers ------------------------------------------------------
#pragma unroll 1
    for (int l = 0; l < 2; ++l) {
#pragma unroll
        for (int mi = 0; mi < 2; ++mi)
#pragma unroll
            for (int ni = 0; ni < 3; ++ni) {
                const int v0 = w * 32 + mi * 16 + (lane >> 4) * 4;
                const int n  = ni * 16 + (lane & 15);
                const unsigned lo = (unsigned)f2bf(acc[mi][ni][0]) | ((unsigned)f2bf(acc[mi][ni][1]) << 16);
                const unsigned hi = (unsigned)f2bf(acc[mi][ni][2]) | ((unsigned)f2bf(acc[mi][ni][3]) << 16);
                *reinterpret_cast<uint2*>(&HT[n * 264 + v0]) = make_uint2(lo, hi);
            }
        __syncthreads();

#pragma unroll
        for (int mi = 0; mi < 2; ++mi)
#pragma unroll
            for (int ni = 0; ni < 3; ++ni) acc[mi][ni] = f32x4{0.f, 0.f, 0.f, 0.f};

        const unsigned short* wl = wsw + (size_t)(t * 2 + l) * (16 * 8 * 64 * 8);
#pragma unroll 1
        for (int kt = 0; kt < 8; ++kt) {
            short8 a[2], bf[3];
#pragma unroll
            for (int mi = 0; mi < 2; ++mi)
                a[mi] = *reinterpret_cast<const short8*>(wl + ((((w * 2 + mi) * 8 + kt) * 64) + lane) * 8);
#pragma unroll
            for (int ni = 0; ni < 3; ++ni)
                bf[ni] = *reinterpret_cast<const short8*>(&HT[(ni * 16 + (lane & 15)) * 264 + kt * 32 + (lane >> 4) * 8]);
#pragma unroll
            for (int mi = 0; mi < 2; ++mi)
#pragma unroll
                for (int ni = 0; ni < 3; ++ni)
                    acc[mi][ni] = __builtin_amdgcn_mfma_f32_16x16x32_bf16(a[mi], bf[ni], acc[mi][ni], 0, 0, 0);
        }
        __syncthreads();   // l==0: HT rewrite; l==1: fst overwrite of HT
    }

    // ---- single-pass epilogue: all waves restage fp32 (swizzled), nt stores -
    // write: fst[n*260 + vswz(v)] as aligned f32x4 (jj 0..3 stays within swz group)
#pragma unroll
    for (int mi = 0; mi < 2; ++mi)
#pragma unroll
        for (int ni = 0; ni < 3; ++ni) {
            const int n  = ni * 16 + (lane & 15);
            const int vb = w * 32 + mi * 16 + (lane >> 4) * 4;
            *reinterpret_cast<f32x4*>(&fst[n * 260 + vswz(vb)]) = acc[mi][ni];
        }
    __syncthreads();

    float* outh = out + (size_t)NB * NR * 3;
#pragma unroll
    for (int i = 0; i < 6; ++i) {
        const int idx = tid + i * 512;            // 0..3071
        const int bl = idx / 192;                 // 16 batches
        const int fo = (idx % 192) * 4;           // 0..764, step 4
        f32x4 v4;
#pragma unroll
        for (int e = 0; e < 4; ++e) {
            const int f = fo + e, c = f % 3, vp = f / 3;      // vp in [0,256)
            v4[e] = fst[(bl * 3 + c) * 260 + vswz(vp)];
        }
        __builtin_nontemporal_store(v4,
            reinterpret_cast<f32x4*>(&outh[(((size_t)(b0 + bl) * NR + r) * (ND * 3)) + fo]));
    }
}

// ---- fallback (round-2 verified VALU kernel) if ws too small ---------------
__global__ __launch_bounds__(256, 3) void residues_fused_fb(
    const float* __restrict__ x, const float* __restrict__ W0,
    const float* __restrict__ Wh, const int* __restrict__ type_ids,
    const int* __restrict__ res_idx, float* __restrict__ out, int n_atoms)
{
    const int tid = threadIdx.x;
    const int r = blockIdx.x >> 4;
    const int b0 = (blockIdx.x & 15) * 8;
    const int ri = res_idx[r], t = type_ids[r];
    __shared__ float dlt[NA][24];
    __shared__ float hA[ND][24];
    __shared__ float hB[ND][24];
    for (int idx = tid; idx < 8 * NA * 3; idx += 256) {
        const int bb = idx / (NA * 3), rem = idx % (NA * 3);
        const int a = rem / 3, c = rem % 3, b = b0 + bb;
        int ca = ri + a; if (ca > n_atoms - 1) ca = n_atoms - 1;
        const float root = x[((size_t)b * n_atoms + (ri + 1)) * 3 + c];
        dlt[a][bb * 3 + c] = x[((size_t)b * n_atoms + ca) * 3 + c] - root;
        if (a == 0) out[((size_t)b * NR + r) * 3 + c] = root;
    }
    __syncthreads();
    {
        const float* w0row = W0 + ((size_t)t * ND + tid) * NA;
        float acc[24];
#pragma unroll
        for (int n = 0; n < 24; ++n) acc[n] = 0.f;
#pragma unroll
        for (int a = 0; a < NA; ++a) {
            const float wv = w0row[a];
#pragma unroll
            for (int n = 0; n < 24; ++n) acc[n] += wv * dlt[a][n];
        }
#pragma unroll
        for (int n = 0; n < 24; ++n) hA[tid][n] = acc[n];
    }
    __syncthreads();
    const float* whbase = Wh + (size_t)t * 2 * ND * ND;
#pragma unroll
    for (int l = 0; l < 2; ++l) {
        const float* wrow = whbase + ((size_t)l * ND + tid) * ND;
        const float (*hin)[24] = (l == 0) ? hA : hB;
        float (*hout)[24]      = (l == 0) ? hB : hA;
        float acc[24];
#pragma unroll
        for (int n = 0; n < 24; ++n) acc[n] = 0.f;
        for (int u = 0; u < ND; ++u) {
            const float wv = wrow[u];
#pragma unroll
            for (int n = 0; n < 24; ++n) acc[n] += wv * hin[u][n];
        }
#pragma unroll
        for (int n = 0; n < 24; ++n) hout[tid][n] = acc[n];
        __syncthreads();
    }
    float* outh = out + (size_t)NB * NR * 3;
#pragma unroll
    for (int bb = 0; bb < 8; ++bb) {
        const size_t base = ((size_t)((b0 + bb) * NR + r)) * (ND * 3);
#pragma unroll
        for (int it = 0; it < 3; ++it) {
            const int g = it * 256 + tid;
            outh[base + g] = hA[g / 3][bb * 3 + g % 3];
        }
    }
}

extern "C" void kernel_launch(void* const* d_in, const int* in_sizes, int n_in,
                              void* d_out, int out_size, void* d_ws, size_t ws_size,
                              hipStream_t stream) {
    const float* x        = (const float*)d_in[0];
    const float* W0       = (const float*)d_in[1];
    const float* Wh       = (const float*)d_in[2];
    const int*   type_ids = (const int*)d_in[3];
    const int*   res_idx  = (const int*)d_in[4];
    float* out = (float*)d_out;
    const int n_atoms = in_sizes[0] / (NB * 3);

    if (ws_size >= WS_NEEDED) {
        unsigned short* wsw = (unsigned short*)d_ws;
        int* rmap = (int*)((char*)d_ws + RMAP_BYTE_OFF);
        prep_all<<<1361, 256, 0, stream>>>(Wh, W0, type_ids, wsw, rmap);
        residues_mfma<<<NR * 8, 512, 0, stream>>>(x, wsw, rmap, type_ids, res_idx, out, n_atoms);
    } else {
        residues_fused_fb<<<NR * 16, 256, 0, stream>>>(x, W0, Wh, type_ids, res_idx, out, n_atoms);
    }
}

// Round 11
// 101.718 us; speedup vs baseline: 1.2927x; 1.0628x over previous
//
#include <hip/hip_runtime.h>

namespace {
constexpr int NB = 128;
constexpr int NR = 512;
constexpr int ND = 256;
constexpr int NA = 14;

using short8 = __attribute__((ext_vector_type(8))) short;
using f32x4  = __attribute__((ext_vector_type(4))) float;

// workspace layout (ushort elements for weights, then rmap ints)
constexpr size_t WH_US  = (size_t)40 * 16 * 8 * 64 * 8;   // 2,621,440
constexpr size_t W0_OFF = WH_US;
constexpr size_t W0_US  = (size_t)20 * 16 * 64 * 8;       // 163,840
constexpr size_t RMAP_BYTE_OFF = (WH_US + W0_US) * 2;     // 5,570,560
constexpr size_t WS_NEEDED = RMAP_BYTE_OFF + NR * sizeof(int);

__device__ __forceinline__ unsigned short f2bf(float f) {
    unsigned int u = __float_as_uint(f);
    u = (u + 0x7FFFu + ((u >> 16) & 1u)) >> 16;           // RNE
    return (unsigned short)u;
}
// v-index bank swizzle (write AND read): breaks v/v+32/v+64 aliasing
// (row stride 260 words == 4 mod 32; v-period 24 within a wave's gather)
__device__ __forceinline__ int vswz(int v) { return v ^ (((v >> 5) & 3) << 3); }
}

// ---- converter: Wh fp32 -> bf16, A-fragment order ---------------------------
__global__ void conv_wh(const float* __restrict__ Wh, unsigned short* __restrict__ ws) {
    int g = blockIdx.x * 256 + threadIdx.x;
    if (g >= 40 * 16 * 8 * 64) return;
    const int lane = g & 63, kt = (g >> 6) & 7, mt = (g >> 9) & 15, tl = g >> 13;
    const int v = mt * 16 + (lane & 15);
    const int u0 = kt * 32 + (lane >> 4) * 8;
    const float* src = Wh + ((size_t)tl * ND + v) * ND + u0;
    unsigned short o[8];
#pragma unroll
    for (int j = 0; j < 8; ++j) o[j] = f2bf(src[j]);
    uint4 pk;
    pk.x = o[0] | ((unsigned)o[1] << 16); pk.y = o[2] | ((unsigned)o[3] << 16);
    pk.z = o[4] | ((unsigned)o[5] << 16); pk.w = o[6] | ((unsigned)o[7] << 16);
    *reinterpret_cast<uint4*>(ws + (size_t)g * 8) = pk;
}

__global__ void conv_w0(const float* __restrict__ W0, unsigned short* __restrict__ ws) {
    int g = blockIdx.x * 256 + threadIdx.x;
    if (g >= 20 * 16 * 64) return;
    const int lane = g & 63, mt = (g >> 6) & 15, t = g >> 10;
    const int v = mt * 16 + (lane & 15);
    const int a0 = (lane >> 4) * 8;
    unsigned short o[8];
#pragma unroll
    for (int j = 0; j < 8; ++j) {
        const int a = a0 + j;
        o[j] = (a < NA) ? f2bf(W0[((size_t)t * ND + v) * NA + a]) : (unsigned short)0;
    }
    uint4 pk;
    pk.x = o[0] | ((unsigned)o[1] << 16); pk.y = o[2] | ((unsigned)o[3] << 16);
    pk.z = o[4] | ((unsigned)o[5] << 16); pk.w = o[6] | ((unsigned)o[7] << 16);
    *reinterpret_cast<uint4*>(ws + W0_OFF + (size_t)g * 8) = pk;
}

// ---- type-sorted residue map (stable counting order, deterministic) --------
__global__ void build_rmap(const int* __restrict__ type_ids, int* __restrict__ rmap) {
    __shared__ int tl[NR];
    const int tid = threadIdx.x;          // 512 threads
    tl[tid] = type_ids[tid];
    __syncthreads();
    const int myt = tl[tid];
    int pos = 0;
    for (int j = 0; j < NR; ++j) {
        const int tj = tl[j];
        pos += (tj < myt) || (tj == myt && j < tid);
    }
    rmap[pos] = tid;
}

// ---- main fused kernel ------------------------------------------------------
// 4096 blocks, 512 threads (8 waves). XCD-affine sorted mapping (r8-proven).
// Tile = 48 cols (16 batches). Wave w owns v in [32w, 32w+32): acc[2][3].
// LDS: HT 25344B + fstc 24960B = 50304B -> 3 blocks/CU at (512,6); no spill
// (r8-measured clean at this config). Epilogue: 2 column-half passes, all
// waves active; swizzled f32x4 restage writes; div-free coalesced nt-stores.
__global__ __launch_bounds__(512, 6) void residues_mfma(
    const float* __restrict__ x, const unsigned short* __restrict__ wsw,
    const int* __restrict__ rmap, const int* __restrict__ type_ids,
    const int* __restrict__ res_idx, float* __restrict__ out, int n_atoms)
{
    const int tid = threadIdx.x, lane = tid & 63, w = tid >> 6;
    const int xcd = blockIdx.x & 7, j = blockIdx.x >> 3;      // j in [0,512)
    const int r = rmap[xcd * 64 + (j >> 3)];
    const int b0 = (j & 7) * 16;
    const int ri = res_idx[r], t = type_ids[r];

    __shared__ __align__(16) unsigned short HT[48 * 264];    // dltT aliases base
    __shared__ __align__(16) float fstc[24 * 260];           // epilogue restage
    unsigned short* dltT = HT;

    // hoist layer-0 A fragments (depend only on t)
    const unsigned short* w0b = wsw + W0_OFF + (size_t)t * (16 * 64 * 8);
    short8 a0[2];
#pragma unroll
    for (int mi = 0; mi < 2; ++mi)
        a0[mi] = *reinterpret_cast<const short8*>(w0b + (((w * 2 + mi) * 64) + lane) * 8);

    // ---- fused stage: dltT (bf16, K padded to 32) + pos_ca -----------------
    {
        const int bl = tid >> 5, k = tid & 31;     // 512 tasks = 16 bl x 32 k
        const float* xb = x + (size_t)(b0 + bl) * n_atoms * 3;
        if (k < 16) {
            int atom = ri + k; if (atom > n_atoms - 1) atom = n_atoms - 1;
            const float* src  = xb + (size_t)atom * 3;
            const float* root = xb + (size_t)(ri + 1) * 3;
#pragma unroll
            for (int c = 0; c < 3; ++c)
                dltT[(bl * 3 + c) * 40 + k] = f2bf(src[c] - root[c]);
            if (k == 1) {
#pragma unroll
                for (int c = 0; c < 3; ++c)
                    out[((size_t)(b0 + bl) * NR + r) * 3 + c] = root[c];
            }
        } else {
#pragma unroll
            for (int c = 0; c < 3; ++c)
                dltT[(bl * 3 + c) * 40 + k] = 0;
        }
    }
    __syncthreads();

    f32x4 acc[2][3];
#pragma unroll
    for (int mi = 0; mi < 2; ++mi)
#pragma unroll
        for (int ni = 0; ni < 3; ++ni) acc[mi][ni] = f32x4{0.f, 0.f, 0.f, 0.f};

    // ---- layer 0: K=32 (padded), A hoisted, B from dltT --------------------
    {
        short8 bf[3];
#pragma unroll
        for (int ni = 0; ni < 3; ++ni)
            bf[ni] = *reinterpret_cast<const short8*>(&dltT[(ni * 16 + (lane & 15)) * 40 + (lane >> 4) * 8]);
#pragma unroll
        for (int mi = 0; mi < 2; ++mi)
#pragma unroll
            for (int ni = 0; ni < 3; ++ni)
                acc[mi][ni] = __builtin_amdgcn_mfma_f32_16x16x32_bf16(a0[mi], bf[ni], acc[mi][ni], 0, 0, 0);
    }
    __syncthreads();   // dltT reads done before HT overwrite (aliased)

    // ---- hidden layers ------------------------------------------------------
#pragma unroll 1
    for (int l = 0; l < 2; ++l) {
#pragma unroll
        for (int mi = 0; mi < 2; ++mi)
#pragma unroll
            for (int ni = 0; ni < 3; ++ni) {
                const int v0 = w * 32 + mi * 16 + (lane >> 4) * 4;
                const int n  = ni * 16 + (lane & 15);
                const unsigned lo = (unsigned)f2bf(acc[mi][ni][0]) | ((unsigned)f2bf(acc[mi][ni][1]) << 16);
                const unsigned hi = (unsigned)f2bf(acc[mi][ni][2]) | ((unsigned)f2bf(acc[mi][ni][3]) << 16);
                *reinterpret_cast<uint2*>(&HT[n * 264 + v0]) = make_uint2(lo, hi);
            }
        __syncthreads();

#pragma unroll
        for (int mi = 0; mi < 2; ++mi)
#pragma unroll
            for (int ni = 0; ni < 3; ++ni) acc[mi][ni] = f32x4{0.f, 0.f, 0.f, 0.f};

        const unsigned short* wl = wsw + (size_t)(t * 2 + l) * (16 * 8 * 64 * 8);
#pragma unroll 1
        for (int kt = 0; kt < 8; ++kt) {
            short8 a[2], bf[3];
#pragma unroll
            for (int mi = 0; mi < 2; ++mi)
                a[mi] = *reinterpret_cast<const short8*>(wl + ((((w * 2 + mi) * 8 + kt) * 64) + lane) * 8);
#pragma unroll
            for (int ni = 0; ni < 3; ++ni)
                bf[ni] = *reinterpret_cast<const short8*>(&HT[(ni * 16 + (lane & 15)) * 264 + kt * 32 + (lane >> 4) * 8]);
#pragma unroll
            for (int mi = 0; mi < 2; ++mi)
#pragma unroll
                for (int ni = 0; ni < 3; ++ni)
                    acc[mi][ni] = __builtin_amdgcn_mfma_f32_16x16x32_bf16(a[mi], bf[ni], acc[mi][ni], 0, 0, 0);
        }
        if (l == 0) __syncthreads();   // HT rewrite next iter; l==1 falls into fstc (separate region)
    }

    // ---- epilogue: 2 column-half passes, all waves active ------------------
    float* outh = out + (size_t)NB * NR * 3;
#pragma unroll 1
    for (int q = 0; q < 2; ++q) {
        // restage: cols n in [24q, 24q+24) -> fstc[n-24q][vswz(v)], f32x4 aligned
#pragma unroll
        for (int mi = 0; mi < 2; ++mi)
#pragma unroll
            for (int ni = 0; ni < 3; ++ni) {
                const int n = ni * 16 + (lane & 15);
                const int nloc = n - 24 * q;
                if (nloc >= 0 && nloc < 24) {
                    const int vb = w * 32 + mi * 16 + (lane >> 4) * 4;
                    *reinterpret_cast<f32x4*>(&fstc[nloc * 260 + vswz(vb)]) = acc[mi][ni];
                }
            }
        __syncthreads();
        // store: wave w -> batch b0+8q+w, contiguous 768 floats, nt f32x4
        {
            const size_t obase = ((size_t)(b0 + 8 * q + w) * NR + r) * (ND * 3);
#pragma unroll
            for (int i = 0; i < 3; ++i) {
                const int f0 = (lane + 64 * i) * 4;        // 0..764 step 4
                int v = f0 / 3;                            // one magic-mul per i
                int c = f0 - v * 3;
                f32x4 o;
#pragma unroll
                for (int e = 0; e < 4; ++e) {
                    o[e] = fstc[(w * 3 + c) * 260 + vswz(v)];
                    ++c; if (c == 3) { c = 0; ++v; }
                }
                __builtin_nontemporal_store(o,
                    reinterpret_cast<f32x4*>(&outh[obase + f0]));
            }
        }
        if (q == 0) __syncthreads();   // fstc consumed before pass-1 overwrite
    }
}

// ---- fallback (round-2 verified VALU kernel) if ws too small ---------------
__global__ __launch_bounds__(256, 3) void residues_fused_fb(
    const float* __restrict__ x, const float* __restrict__ W0,
    const float* __restrict__ Wh, const int* __restrict__ type_ids,
    const int* __restrict__ res_idx, float* __restrict__ out, int n_atoms)
{
    const int tid = threadIdx.x;
    const int r = blockIdx.x >> 4;
    const int b0 = (blockIdx.x & 15) * 8;
    const int ri = res_idx[r], t = type_ids[r];
    __shared__ float dlt[NA][24];
    __shared__ float hA[ND][24];
    __shared__ float hB[ND][24];
    for (int idx = tid; idx < 8 * NA * 3; idx += 256) {
        const int bb = idx / (NA * 3), rem = idx % (NA * 3);
        const int a = rem / 3, c = rem % 3, b = b0 + bb;
        int ca = ri + a; if (ca > n_atoms - 1) ca = n_atoms - 1;
        const float root = x[((size_t)b * n_atoms + (ri + 1)) * 3 + c];
        dlt[a][bb * 3 + c] = x[((size_t)b * n_atoms + ca) * 3 + c] - root;
        if (a == 0) out[((size_t)b * NR + r) * 3 + c] = root;
    }
    __syncthreads();
    {
        const float* w0row = W0 + ((size_t)t * ND + tid) * NA;
        float acc[24];
#pragma unroll
        for (int n = 0; n < 24; ++n) acc[n] = 0.f;
#pragma unroll
        for (int a = 0; a < NA; ++a) {
            const float wv = w0row[a];
#pragma unroll
            for (int n = 0; n < 24; ++n) acc[n] += wv * dlt[a][n];
        }
#pragma unroll
        for (int n = 0; n < 24; ++n) hA[tid][n] = acc[n];
    }
    __syncthreads();
    const float* whbase = Wh + (size_t)t * 2 * ND * ND;
#pragma unroll
    for (int l = 0; l < 2; ++l) {
        const float* wrow = whbase + ((size_t)l * ND + tid) * ND;
        const float (*hin)[24] = (l == 0) ? hA : hB;
        float (*hout)[24]      = (l == 0) ? hB : hA;
        float acc[24];
#pragma unroll
        for (int n = 0; n < 24; ++n) acc[n] = 0.f;
        for (int u = 0; u < ND; ++u) {
            const float wv = wrow[u];
#pragma unroll
            for (int n = 0; n < 24; ++n) acc[n] += wv * hin[u][n];
        }
#pragma unroll
        for (int n = 0; n < 24; ++n) hout[tid][n] = acc[n];
        __syncthreads();
    }
    float* outh = out + (size_t)NB * NR * 3;
#pragma unroll
    for (int bb = 0; bb < 8; ++bb) {
        const size_t base = ((size_t)((b0 + bb) * NR + r)) * (ND * 3);
#pragma unroll
        for (int it = 0; it < 3; ++it) {
            const int g = it * 256 + tid;
            outh[base + g] = hA[g / 3][bb * 3 + g % 3];
        }
    }
}

extern "C" void kernel_launch(void* const* d_in, const int* in_sizes, int n_in,
                              void* d_out, int out_size, void* d_ws, size_t ws_size,
                              hipStream_t stream) {
    const float* x        = (const float*)d_in[0];
    const float* W0       = (const float*)d_in[1];
    const float* Wh       = (const float*)d_in[2];
    const int*   type_ids = (const int*)d_in[3];
    const int*   res_idx  = (const int*)d_in[4];
    float* out = (float*)d_out;
    const int n_atoms = in_sizes[0] / (NB * 3);

    if (ws_size >= WS_NEEDED) {
        unsigned short* wsw = (unsigned short*)d_ws;
        int* rmap = (int*)((char*)d_ws + RMAP_BYTE_OFF);
        conv_wh<<<(40 * 16 * 8 * 64 + 255) / 256, 256, 0, stream>>>(Wh, wsw);
        conv_w0<<<(20 * 16 * 64 + 255) / 256, 256, 0, stream>>>(W0, wsw);
        build_rmap<<<1, NR, 0, stream>>>(type_ids, rmap);
        residues_mfma<<<NR * 8, 512, 0, stream>>>(x, wsw, rmap, type_ids, res_idx, out, n_atoms);
    } else {
        residues_fused_fb<<<NR * 16, 256, 0, stream>>>(x, W0, Wh, type_ids, res_idx, out, n_atoms);
    }
}